// Round 1
// 1139.372 us; speedup vs baseline: 1.0039x; 1.0039x over previous
//
#include <hip/hip_runtime.h>
#include <math.h>

// Problem constants (fixed by the reference).
#define DD 2001      // feature dim
#define CC 20        // classes
#define NN 100000    // rows
#define REGC 0.001f

#define NRG 1563     // ceil(NN / 64) row groups, 64 rows per block

__device__ __forceinline__ float4 ld4(const float* p) {
  return *reinterpret_cast<const float4*>(p);
}

// Fused kernel: one 256-thread block (4 waves) per 64 rows. Wave w computes
// the D-slice w of the same 64 rows (chunk ranges {32,31,31,31} x 16 floats,
// wave 3 adds the d=2000 tail). Each wave stages X through its own LDS
// region (coalesced 64B-per-row global loads) and the W chunk through LDS
// consumed via broadcast ds_read_b128. After the K-loop, partial scores are
// exchanged through LDS (overlaid on the X-staging buffer: exactly
// 4*64*20 floats) and wave 0 computes the per-row loss + block reduction.
// No global partials, no epilogue kernel.
__global__ __launch_bounds__(256, 4) void loss_fused(
    const float* __restrict__ X,
    const float* __restrict__ Wt,    // [DD][CC] transposed weights
    const int* __restrict__ Y,
    float* __restrict__ out) {
  __shared__ float xs[4][64 * 20];   // per-wave X stage; 20480 B. Overlaid
                                     // with partials [4][64][20] after K-loop.
  __shared__ float wc[4][16 * 20];   // per-wave W chunk [d=16][c=20]; 5120 B
  const int tid = threadIdx.x;
  const int lane = tid & 63;
  const int wid = tid >> 6;          // D-slice index (was blockIdx.y)
  const int rowbase = blockIdx.x * 64;
  const int row0 = rowbase + lane;
  const bool valid = row0 < NN;

  // Chunk ranges over 125 full 16-float chunks: {32,31,31,31}; wave 3 adds d=2000.
  const int ch0 = (wid == 0) ? 0 : (32 + 31 * (wid - 1));
  const int nch = (wid == 0) ? 32 : 31;

  // X staging map: instr q (0..3): lane l -> row rowbase + q*16 + (l>>2),
  // float4 (l&3). Per instr: 16 rows x 64 B contiguous segments.
  const int srow = lane >> 2;
  const int sf = lane & 3;
  unsigned sb[4];
#pragma unroll
  for (int q = 0; q < 4; ++q) {
    int r = rowbase + q * 16 + srow;
    r = r < NN ? r : NN - 1;           // clamp OOB rows (results discarded)
    sb[q] = (unsigned)r * DD + sf * 4u;
  }

  float acc[CC];
#pragma unroll
  for (int c = 0; c < CC; ++c) acc[c] = 0.f;

  // Prefetch chunk ch0 into registers.
  float4 xa[4];
  float4 wa0, wa1;
  {
    const unsigned doff = (unsigned)ch0 * 16u;
#pragma unroll
    for (int q = 0; q < 4; ++q) xa[q] = ld4(X + sb[q] + doff);
    const float* wp = Wt + (size_t)ch0 * (16 * CC);   // 320 floats per chunk
    wa0 = ld4(wp + lane * 4);                          // floats 0..255
    wa1 = (lane < 16) ? ld4(wp + 256 + lane * 4)       // floats 256..319
                      : float4{0, 0, 0, 0};
  }

#pragma unroll 1
  for (int ch = 0; ch < nch; ++ch) {
    // Stage current chunk regs -> LDS. Each wave touches only xs[wid]/wc[wid]:
    // in-order DS pipe within the wave, no __syncthreads needed.
#pragma unroll
    for (int q = 0; q < 4; ++q)
      *reinterpret_cast<float4*>(&xs[wid][(q * 16 + srow) * 20 + sf * 4]) = xa[q];
    *reinterpret_cast<float4*>(&wc[wid][lane * 4]) = wa0;
    if (lane < 16) *reinterpret_cast<float4*>(&wc[wid][256 + lane * 4]) = wa1;

    // Prefetch next chunk during compute.
    if (ch + 1 < nch) {
      const unsigned doff = (unsigned)(ch0 + ch + 1) * 16u;
#pragma unroll
      for (int q = 0; q < 4; ++q) xa[q] = ld4(X + sb[q] + doff);
      const float* wp = Wt + (size_t)(ch0 + ch + 1) * (16 * CC);
      wa0 = ld4(wp + lane * 4);
      if (lane < 16) wa1 = ld4(wp + 256 + lane * 4);
    }

    // Compute: 16 d-values x 20 classes. W via broadcast b128 LDS reads.
#pragma unroll
    for (int f = 0; f < 4; ++f) {
      const float4 xv = *reinterpret_cast<const float4*>(&xs[wid][lane * 20 + f * 4]);
      const float xj[4] = {xv.x, xv.y, xv.z, xv.w};
#pragma unroll
      for (int j = 0; j < 4; ++j) {
        const int d = f * 4 + j;
        const float xx = xj[j];
        const float4 w0 = *reinterpret_cast<const float4*>(&wc[wid][d * 20 + 0]);
        const float4 w1 = *reinterpret_cast<const float4*>(&wc[wid][d * 20 + 4]);
        const float4 w2 = *reinterpret_cast<const float4*>(&wc[wid][d * 20 + 8]);
        const float4 w3 = *reinterpret_cast<const float4*>(&wc[wid][d * 20 + 12]);
        const float4 w4 = *reinterpret_cast<const float4*>(&wc[wid][d * 20 + 16]);
        acc[0] = fmaf(xx, w0.x, acc[0]);   acc[1] = fmaf(xx, w0.y, acc[1]);
        acc[2] = fmaf(xx, w0.z, acc[2]);   acc[3] = fmaf(xx, w0.w, acc[3]);
        acc[4] = fmaf(xx, w1.x, acc[4]);   acc[5] = fmaf(xx, w1.y, acc[5]);
        acc[6] = fmaf(xx, w1.z, acc[6]);   acc[7] = fmaf(xx, w1.w, acc[7]);
        acc[8] = fmaf(xx, w2.x, acc[8]);   acc[9] = fmaf(xx, w2.y, acc[9]);
        acc[10] = fmaf(xx, w2.z, acc[10]); acc[11] = fmaf(xx, w2.w, acc[11]);
        acc[12] = fmaf(xx, w3.x, acc[12]); acc[13] = fmaf(xx, w3.y, acc[13]);
        acc[14] = fmaf(xx, w3.z, acc[14]); acc[15] = fmaf(xx, w3.w, acc[15]);
        acc[16] = fmaf(xx, w4.x, acc[16]); acc[17] = fmaf(xx, w4.y, acc[17]);
        acc[18] = fmaf(xx, w4.z, acc[18]); acc[19] = fmaf(xx, w4.w, acc[19]);
      }
    }
  }

  // Tail d = 2000 (wave 3 only): per-lane X read + wave-uniform W (tiny).
  if (wid == 3) {
    const int r = valid ? row0 : NN - 1;
    const float xx = X[(size_t)r * DD + 2000];
#pragma unroll
    for (int c = 0; c < CC; ++c)
      acc[c] = fmaf(xx, Wt[2000 * CC + c], acc[c]);
  }

  // Exchange partials through LDS, overlaid on xs: pl[w][lane][c].
  // Wave w writes exactly its own xs[w] region (floats [w*1280, w*1280+1280)),
  // so no barrier is needed before the writes.
  float* pl = &xs[0][0];
  {
    const int base = (wid * 64 + lane) * CC;
#pragma unroll
    for (int f = 0; f < 5; ++f) {
      float4 v = {acc[f * 4 + 0], acc[f * 4 + 1], acc[f * 4 + 2], acc[f * 4 + 3]};
      *reinterpret_cast<float4*>(&pl[base + f * 4]) = v;
    }
  }
  __syncthreads();

  // Epilogue on wave 0: per-row loss, 64-lane reduce, one atomic per block.
  if (tid < 64) {
    float sc[CC];
#pragma unroll
    for (int c = 0; c < CC; ++c) {
      float s = 0.f;
#pragma unroll
      for (int w = 0; w < 4; ++w) s += pl[(w * 64 + lane) * CC + c];
      sc[c] = s;
    }

    float mx = -3.402823466e38f;
#pragma unroll
    for (int c = 0; c < CC; ++c) mx = fmaxf(mx, -sc[c]);
    float se = 0.f;
#pragma unroll
    for (int c = 0; c < CC; ++c) se += __expf(-sc[c] - mx);
    const int y = valid ? Y[row0] : 0;
    float picked = 0.f;
#pragma unroll
    for (int c = 0; c < CC; ++c) picked = (c == y) ? sc[c] : picked;
    float li = valid ? (picked + mx + __logf(se)) : 0.f;

#pragma unroll
    for (int off = 32; off > 0; off >>= 1) li += __shfl_xor(li, off, 64);
    if (tid == 0) atomicAdd(out, li * (1.0f / NN));
  }
}

// Runs FIRST: transpose W -> Wt[d][c]; block 0 additionally computes
// out[0] = REG * ||init_weights||_F (plain store, clears poison).
__global__ __launch_bounds__(256) void prep(
    const float* __restrict__ W,
    const float* __restrict__ IW,
    float* __restrict__ Wt,
    float* __restrict__ out) {
  const int i = blockIdx.x * 256 + threadIdx.x;
  if (i < CC * DD) {
    const int c = i / DD;
    const int d = i - c * DD;
    Wt[d * CC + c] = W[i];
  }
  if (blockIdx.x == 0) {
    __shared__ float red[256];
    float s = 0.f;
    for (int j = threadIdx.x; j < CC * DD; j += 256) {
      const float v = IW[j];
      s += v * v;
    }
    red[threadIdx.x] = s;
    __syncthreads();
    for (int w = 128; w > 0; w >>= 1) {
      if (threadIdx.x < w) red[threadIdx.x] += red[threadIdx.x + w];
      __syncthreads();
    }
    if (threadIdx.x == 0) out[0] = REGC * sqrtf(red[0]);
  }
}

extern "C" void kernel_launch(void* const* d_in, const int* in_sizes, int n_in,
                              void* d_out, int out_size, void* d_ws, size_t ws_size,
                              hipStream_t stream) {
  const float* W  = (const float*)d_in[0];   // weights [C, D]
  const float* X  = (const float*)d_in[1];   // X [N, D]
  const int*   Y  = (const int*)d_in[2];     // Y [N]
  const float* IW = (const float*)d_in[3];   // init_weights [C, D]
  float* out = (float*)d_out;

  float* Wt = (float*)d_ws;                  // 160 KB transposed weights only

  // 1) prep: reg term into out (clears poison) + W transpose, one launch
  prep<<<(CC * DD + 255) / 256, 256, 0, stream>>>(W, IW, Wt, out);
  // 2) fused main kernel: 1563 blocks x 256 threads (4 waves = 4 D-slices),
  //    in-block partial reduce + per-row loss + one atomic per block
  loss_fused<<<NRG, 256, 0, stream>>>(X, Wt, Y, out);
}